// Round 2
// baseline (435.435 us; speedup 1.0000x reference)
//
#include <hip/hip_runtime.h>

#define HH 16
#define DKK 64
#define SS 2048
#define BB 2
#define DD 1024

typedef __attribute__((ext_vector_type(4))) float f32x4;
typedef __attribute__((ext_vector_type(8))) short bf16x8;
typedef __attribute__((ext_vector_type(4))) short s16x4;
typedef __attribute__((ext_vector_type(2))) int i32x2;

__device__ __forceinline__ short bf16b(float f) {
    union { float f; unsigned u; } x; x.f = f;
    unsigned r = (x.u + 0x7fffu + ((x.u >> 16) & 1u)) >> 16;
    return (short)r;
}

__device__ __forceinline__ unsigned f2u(float f) {
    union { float f; unsigned u; } x; x.f = f;
    return x.u;
}

__device__ __forceinline__ f32x4 mfma16(bf16x8 a, bf16x8 b, f32x4 c) {
    return __builtin_amdgcn_mfma_f32_16x16x32_bf16(a, b, c, 0, 0, 0);
}

__device__ __forceinline__ void lds16(const short* g, short* l) {
    __builtin_amdgcn_global_load_lds(
        (const __attribute__((address_space(1))) void*)g,
        (__attribute__((address_space(3))) void*)l, 16, 0, 0);
}

// ---------------- fp32 -> bf16 cast (contiguous) ----------------
__global__ __launch_bounds__(256) void cvt_bf16(const float* __restrict__ x,
                                                short* __restrict__ y, int n) {
    int i = (blockIdx.x * 256 + threadIdx.x) * 4;
    if (i >= n) return;
    f32x4 v = *(const f32x4*)(x + i);
    s16x4 o;
    o.x = bf16b(v.x); o.y = bf16b(v.y); o.z = bf16b(v.z); o.w = bf16b(v.w);
    *(s16x4*)(y + i) = o;
}

// ---------------- weight transpose+cast: W[K][N] fp32 -> Wt[N][K] bf16 ----------------
__global__ __launch_bounds__(256) void transpose_w(
    const float* __restrict__ W0, const float* __restrict__ W1,
    const float* __restrict__ W2, const float* __restrict__ W3,
    short* __restrict__ T0, short* __restrict__ T1,
    short* __restrict__ T2, short* __restrict__ T3) {
    const float* W; short* T;
    switch (blockIdx.z) {
        case 0: W = W0; T = T0; break;
        case 1: W = W1; T = T1; break;
        case 2: W = W2; T = T2; break;
        default: W = W3; T = T3; break;
    }
    __shared__ short tile[32][33];
    int n0 = blockIdx.x * 32, k0 = blockIdx.y * 32;
    int tx = threadIdx.x & 31;
    int ty = (threadIdx.x >> 5) * 4;
#pragma unroll
    for (int i = 0; i < 4; i++)
        tile[ty + i][tx] = bf16b(W[(k0 + ty + i) * DD + n0 + tx]);
    __syncthreads();
#pragma unroll
    for (int i = 0; i < 4; i++)
        T[(n0 + ty + i) * DD + k0 + tx] = tile[tx][ty + i];
}

// ---------------- bias table: tab[h][delta+2047] = bias * log2(e) ----------------
__global__ __launch_bounds__(256) void build_bias(const float* __restrict__ rb,
                                                  float* __restrict__ tab) {
    int idx = blockIdx.x * 256 + threadIdx.x;
    if (idx >= HH * 4095) return;
    int h = idx / 4095, d = idx % 4095;
    int rel = d - 2047; // k - q
    int bucket = (rel > 0) ? 16 : 0;
    unsigned r = (rel < 0) ? (unsigned)(-rel) : (unsigned)rel;
    int add;
    if (r < 8) add = (int)r;
    else {
        int e = 31 - __clz(r);
        unsigned long long r2 = (unsigned long long)r * (unsigned long long)r;
        int f = 2 * e + ((r2 >= (2ull << (2 * e))) ? 1 : 0); // floor(2*log2 r)
        add = 8 + (f - 6);
        if (add > 15) add = 15;
    }
    bucket += add;
    tab[h * 4095 + d] = rb[bucket * HH + h] * 1.44269504f;
}

// ---------------- 128x128 tile bf16 GEMM: C = A[M][K] * Bt[N][K]^T ----------------
// m97-style: global_load_lds width=16 staging (LDS layout = tid*16B, lane-contiguous)
template <int EPI>
__global__ __launch_bounds__(256) void gemm_bt(
    const short* __restrict__ A,
    const short* __restrict__ Bq, const short* __restrict__ Bk, const short* __restrict__ Bv,
    short* __restrict__ Cq, short* __restrict__ Ck, short* __restrict__ Cvt,
    float* __restrict__ Cout) {
    const int K = 1024, N = 1024;
    __shared__ short As[128 * 32];
    __shared__ short Bs[128 * 32];
    int tid = threadIdx.x;
    int wave = tid >> 6, lane = tid & 63;
    int quad = lane >> 4, l16 = lane & 15;
    int m0 = blockIdx.y * 128, n0 = blockIdx.x * 128;
    const short* Bt = Bq;
    if (EPI == 0) { if (blockIdx.z == 1) Bt = Bk; else if (blockIdx.z == 2) Bt = Bv; }

    int wm = (wave & 1) * 64, wn = (wave >> 1) * 64;
    int r0 = tid >> 2, c0 = (tid & 3) * 8;

    f32x4 acc[4][4];
#pragma unroll
    for (int i = 0; i < 4; i++)
#pragma unroll
        for (int j = 0; j < 4; j++) acc[i][j] = (f32x4){0.f, 0.f, 0.f, 0.f};

    for (int k0 = 0; k0 < K; k0 += 32) {
        __syncthreads(); // previous iter's frag reads done
        lds16(A + (size_t)(m0 + r0) * K + k0 + c0, As + wave * 512);
        lds16(A + (size_t)(m0 + 64 + r0) * K + k0 + c0, As + 2048 + wave * 512);
        lds16(Bt + (size_t)(n0 + r0) * K + k0 + c0, Bs + wave * 512);
        lds16(Bt + (size_t)(n0 + 64 + r0) * K + k0 + c0, Bs + 2048 + wave * 512);
        __syncthreads(); // drains vmcnt (global_load_lds) before reads
        bf16x8 af[4], bfr[4];
#pragma unroll
        for (int t = 0; t < 4; t++) {
            af[t] = *(const bf16x8*)(As + (wm + t * 16 + l16) * 32 + quad * 8);
            bfr[t] = *(const bf16x8*)(Bs + (wn + t * 16 + l16) * 32 + quad * 8);
        }
#pragma unroll
        for (int mt = 0; mt < 4; mt++)
#pragma unroll
            for (int nt = 0; nt < 4; nt++)
                acc[mt][nt] = mfma16(af[mt], bfr[nt], acc[mt][nt]);
    }

#pragma unroll
    for (int mt = 0; mt < 4; mt++) {
#pragma unroll
        for (int nt = 0; nt < 4; nt++) {
#pragma unroll
            for (int r = 0; r < 4; r++) {
                int gm = m0 + wm + mt * 16 + quad * 4 + r;
                int gn = n0 + wn + nt * 16 + l16;
                float v = acc[mt][nt][r];
                if (EPI == 1) {
                    Cout[(size_t)gm * N + gn] = v;
                } else {
                    int b = gm >> 11, s = gm & 2047;
                    int h = gn >> 6, dk = gn & 63;
                    short bv = bf16b(v);
                    if (blockIdx.z == 0)
                        Cq[(((size_t)(b * HH + h)) * SS + s) * DKK + dk] = bv;
                    else if (blockIdx.z == 1)
                        Ck[(((size_t)(b * HH + h)) * SS + s) * DKK + dk] = bv;
                    else
                        Cvt[(((size_t)(b * HH + h)) * DKK + dk) * SS + s] = bv;
                }
            }
        }
    }
}

// ---------------- flash-style attention, no online max ----------------
// grid (S/64, B*H), block 256 = 4 waves; wave owns 16 q-rows, 64 keys/iter.
// S^T orientation: QK^T computed as mfma(K-frag, Q-frag) so a lane's 4 scores
// are 4 consecutive keys -> packed ds_write_b64. XOR-swizzled P layout hits
// the bank floor on both write (4-way/b64) and read (8-way/b128).
// l (row-sum of bf16 P) via ones-column MFMA -> consistent with PV numerator.
__global__ __launch_bounds__(256) void attn(
    const short* __restrict__ Q, const short* __restrict__ Kmat,
    const short* __restrict__ Vt, const float* __restrict__ btab,
    short* __restrict__ O) {
    __shared__ float bias_s[4096];
    __shared__ short P_s[4][16 * 64];
    int tid = threadIdx.x;
    int wave = tid >> 6, lane = tid & 63;
    int quad = lane >> 4, l16 = lane & 15;
    int bh = blockIdx.y;
    int h = bh & 15, b = bh >> 4;
    int q0 = blockIdx.x * 64 + wave * 16;

    const float* bt = btab + h * 4095;
    for (int i = tid; i < 4095; i += 256) bias_s[i] = bt[i];
    __syncthreads();

    const short* Qb = Q + (size_t)bh * SS * DKK;
    const short* Kb = Kmat + (size_t)bh * SS * DKK;
    const short* Vb = Vt + (size_t)bh * DKK * SS;

    bf16x8 qf0 = *(const bf16x8*)(Qb + (q0 + l16) * DKK + quad * 8);
    bf16x8 qf1 = *(const bf16x8*)(Qb + (q0 + l16) * DKK + 32 + quad * 8);

    f32x4 o[4];
#pragma unroll
    for (int i = 0; i < 4; i++) o[i] = (f32x4){0.f, 0.f, 0.f, 0.f};
    f32x4 lacc = (f32x4){0.f, 0.f, 0.f, 0.f};

    bf16x8 onesf;
    short onev = (l16 == 0) ? (short)0x3F80 : (short)0;
#pragma unroll
    for (int i = 0; i < 8; i++) onesf[i] = onev;

    short* Pw = &P_s[wave][0];
    int gxor = l16 & 7;
    int ghalf = quad >> 1;
    int wbase = l16 * 64 + (quad & 1) * 4;              // + g*8 (shorts)
    int ra0 = l16 * 64 + ((quad ^ gxor) * 8);           // pf0 read (shorts)
    int ra1 = l16 * 64 + (((4 + quad) ^ gxor) * 8);     // pf1 read
    int dconst = 2047 + quad * 4 - q0 - l16;            // + kc + kt*16 + r

    for (int kc = 0; kc < SS; kc += 64) {
        // ---- QK^T (transposed): S^T[key][q] ----
        bf16x8 kf[4][2];
#pragma unroll
        for (int kt = 0; kt < 4; kt++) {
            kf[kt][0] = *(const bf16x8*)(Kb + (kc + kt * 16 + l16) * DKK + quad * 8);
            kf[kt][1] = *(const bf16x8*)(Kb + (kc + kt * 16 + l16) * DKK + 32 + quad * 8);
        }
        f32x4 s[4];
#pragma unroll
        for (int kt = 0; kt < 4; kt++) {
            s[kt] = mfma16(kf[kt][0], qf0, (f32x4){0.f, 0.f, 0.f, 0.f});
            s[kt] = mfma16(kf[kt][1], qf1, s[kt]);
        }
        // ---- V frags: issue global loads early ----
        bf16x8 vf[4][2];
#pragma unroll
        for (int nt = 0; nt < 4; nt++) {
            vf[nt][0] = *(const bf16x8*)(Vb + (size_t)(nt * 16 + l16) * SS + kc + quad * 8);
            vf[nt][1] = *(const bf16x8*)(Vb + (size_t)(nt * 16 + l16) * SS + kc + 32 + quad * 8);
        }
        // ---- p = exp(s + bias) = 2^(s*log2e + bias*log2e); pack + LDS write ----
#pragma unroll
        for (int kt = 0; kt < 4; kt++) {
            unsigned u[4];
#pragma unroll
            for (int r = 0; r < 4; r++) {
                float bv = bias_s[dconst + kc + kt * 16 + r];
                float p = __builtin_amdgcn_exp2f(fmaf(s[kt][r], 1.44269504f, bv));
                u[r] = f2u(p) + 0x8000u; // round-half-up to bf16 in high 16
            }
            unsigned d0 = __builtin_amdgcn_perm(u[1], u[0], 0x07060302u);
            unsigned d1 = __builtin_amdgcn_perm(u[3], u[2], 0x07060302u);
            int g = (kt * 2 + ghalf) ^ gxor;
            *(i32x2*)(Pw + wbase + g * 8) = (i32x2){(int)d0, (int)d1};
        }
        // wave-local LDS exchange: DS pipe is in-order per wave; just stop the
        // compiler from reordering the read above the write.
        __asm__ __volatile__("" ::: "memory");
        bf16x8 pf0 = *(const bf16x8*)(Pw + ra0);
        bf16x8 pf1 = *(const bf16x8*)(Pw + ra1);
        // ---- row-sum via ones-column MFMA ----
        lacc = mfma16(pf0, onesf, lacc);
        lacc = mfma16(pf1, onesf, lacc);
        // ---- PV ----
#pragma unroll
        for (int nt = 0; nt < 4; nt++) {
            o[nt] = mfma16(pf0, vf[nt][0], o[nt]);
            o[nt] = mfma16(pf1, vf[nt][1], o[nt]);
        }
    }

    float inv[4];
#pragma unroll
    for (int r = 0; r < 4; r++) {
        float l = __shfl(lacc[r], lane & 48); // broadcast from l16==0 of this quad
        inv[r] = 1.f / l;
    }
#pragma unroll
    for (int nt = 0; nt < 4; nt++)
#pragma unroll
        for (int r = 0; r < 4; r++) {
            int qrow = q0 + quad * 4 + r;
            int dk = nt * 16 + l16;
            O[((size_t)(b * SS + qrow)) * (HH * DKK) + h * DKK + dk] =
                bf16b(o[nt][r] * inv[r]);
        }
}

extern "C" void kernel_launch(void* const* d_in, const int* in_sizes, int n_in,
                              void* d_out, int out_size, void* d_ws, size_t ws_size,
                              hipStream_t stream) {
    const float* hs = (const float*)d_in[0];
    const float* Wq = (const float*)d_in[1];
    const float* Wk = (const float*)d_in[2];
    const float* Wv = (const float*)d_in[3];
    const float* Wo = (const float*)d_in[4];
    const float* rb = (const float*)d_in[5];
    float* out = (float*)d_out;

    char* ws = (char*)d_ws;
    size_t off = 0;
    auto alloc = [&](size_t bytes) -> void* {
        void* p = (void*)(ws + off);
        off += (bytes + 255) & ~(size_t)255;
        return p;
    };
    const size_t M = (size_t)BB * SS; // 4096
    short* hsb = (short*)alloc(M * DD * 2);
    short* WqT = (short*)alloc((size_t)DD * DD * 2);
    short* WkT = (short*)alloc((size_t)DD * DD * 2);
    short* WvT = (short*)alloc((size_t)DD * DD * 2);
    short* WoT = (short*)alloc((size_t)DD * DD * 2);
    short* Qb  = (short*)alloc(M * DD * 2);
    short* Kb  = (short*)alloc(M * DD * 2);
    short* VTb = (short*)alloc(M * DD * 2);
    short* Ab  = (short*)alloc(M * DD * 2);
    float* btab = (float*)alloc((size_t)HH * 4095 * 4);

    int nHS = (int)(M * DD);
    cvt_bf16<<<nHS / 1024, 256, 0, stream>>>(hs, hsb, nHS);
    transpose_w<<<dim3(32, 32, 4), 256, 0, stream>>>(Wq, Wk, Wv, Wo, WqT, WkT, WvT, WoT);
    build_bias<<<(HH * 4095 + 255) / 256, 256, 0, stream>>>(rb, btab);
    gemm_bt<0><<<dim3(8, 32, 3), 256, 0, stream>>>(hsb, WqT, WkT, WvT, Qb, Kb, VTb, nullptr);
    attn<<<dim3(32, 32), 256, 0, stream>>>(Qb, Kb, VTb, btab, Ab);
    gemm_bt<1><<<dim3(8, 32, 1), 256, 0, stream>>>(Ab, WoT, nullptr, nullptr,
                                                   nullptr, nullptr, nullptr, out);
}

// Round 3
// 384.870 us; speedup vs baseline: 1.1314x; 1.1314x over previous
//
#include <hip/hip_runtime.h>

#define HH 16
#define DKK 64
#define SS 2048
#define BB 2
#define DD 1024

typedef __attribute__((ext_vector_type(4))) float f32x4;
typedef __attribute__((ext_vector_type(8))) short bf16x8;
typedef __attribute__((ext_vector_type(4))) short s16x4;
typedef __attribute__((ext_vector_type(2))) int i32x2;

__device__ __forceinline__ short bf16b(float f) {
    union { float f; unsigned u; } x; x.f = f;
    unsigned r = (x.u + 0x7fffu + ((x.u >> 16) & 1u)) >> 16;
    return (short)r;
}

__device__ __forceinline__ unsigned f2u(float f) {
    union { float f; unsigned u; } x; x.f = f;
    return x.u;
}

__device__ __forceinline__ f32x4 mfma16(bf16x8 a, bf16x8 b, f32x4 c) {
    return __builtin_amdgcn_mfma_f32_16x16x32_bf16(a, b, c, 0, 0, 0);
}

__device__ __forceinline__ void lds16(const short* g, short* l) {
    __builtin_amdgcn_global_load_lds(
        (const __attribute__((address_space(1))) void*)g,
        (__attribute__((address_space(3))) void*)l, 16, 0, 0);
}

// ---------------- fp32 -> bf16 cast (contiguous) ----------------
__global__ __launch_bounds__(256) void cvt_bf16(const float* __restrict__ x,
                                                short* __restrict__ y, int n) {
    int i = (blockIdx.x * 256 + threadIdx.x) * 4;
    if (i >= n) return;
    f32x4 v = *(const f32x4*)(x + i);
    s16x4 o;
    o.x = bf16b(v.x); o.y = bf16b(v.y); o.z = bf16b(v.z); o.w = bf16b(v.w);
    *(s16x4*)(y + i) = o;
}

// ---------------- weight transpose+cast: W[K][N] fp32 -> Wt[N][K] bf16 ----------------
__global__ __launch_bounds__(256) void transpose_w(
    const float* __restrict__ W0, const float* __restrict__ W1,
    const float* __restrict__ W2, const float* __restrict__ W3,
    short* __restrict__ T0, short* __restrict__ T1,
    short* __restrict__ T2, short* __restrict__ T3) {
    const float* W; short* T;
    switch (blockIdx.z) {
        case 0: W = W0; T = T0; break;
        case 1: W = W1; T = T1; break;
        case 2: W = W2; T = T2; break;
        default: W = W3; T = T3; break;
    }
    __shared__ short tile[32][33];
    int n0 = blockIdx.x * 32, k0 = blockIdx.y * 32;
    int tx = threadIdx.x & 31;
    int ty = (threadIdx.x >> 5) * 4;
#pragma unroll
    for (int i = 0; i < 4; i++)
        tile[ty + i][tx] = bf16b(W[(k0 + ty + i) * DD + n0 + tx]);
    __syncthreads();
#pragma unroll
    for (int i = 0; i < 4; i++)
        T[(n0 + ty + i) * DD + k0 + tx] = tile[tx][ty + i];
}

// ---------------- bias table: tab[h][delta+2047] = bias * log2(e) ----------------
__global__ __launch_bounds__(256) void build_bias(const float* __restrict__ rb,
                                                  float* __restrict__ tab) {
    int idx = blockIdx.x * 256 + threadIdx.x;
    if (idx >= HH * 4095) return;
    int h = idx / 4095, d = idx % 4095;
    int rel = d - 2047; // k - q
    int bucket = (rel > 0) ? 16 : 0;
    unsigned r = (rel < 0) ? (unsigned)(-rel) : (unsigned)rel;
    int add;
    if (r < 8) add = (int)r;
    else {
        int e = 31 - __clz(r);
        unsigned long long r2 = (unsigned long long)r * (unsigned long long)r;
        int f = 2 * e + ((r2 >= (2ull << (2 * e))) ? 1 : 0); // floor(2*log2 r)
        add = 8 + (f - 6);
        if (add > 15) add = 15;
    }
    bucket += add;
    tab[h * 4095 + d] = rb[bucket * HH + h] * 1.44269504f;
}

// ---------------- 128x128 tile bf16 GEMM: C = A[M][K] * Bt[N][K]^T ----------------
template <int EPI>
__global__ __launch_bounds__(256) void gemm_bt(
    const short* __restrict__ A,
    const short* __restrict__ Bq, const short* __restrict__ Bk, const short* __restrict__ Bv,
    short* __restrict__ Cq, short* __restrict__ Ck, short* __restrict__ Cvt,
    float* __restrict__ Cout) {
    const int K = 1024, N = 1024;
    __shared__ short As[128 * 32];
    __shared__ short Bs[128 * 32];
    int tid = threadIdx.x;
    int wave = tid >> 6, lane = tid & 63;
    int quad = lane >> 4, l16 = lane & 15;
    int m0 = blockIdx.y * 128, n0 = blockIdx.x * 128;
    const short* Bt = Bq;
    if (EPI == 0) { if (blockIdx.z == 1) Bt = Bk; else if (blockIdx.z == 2) Bt = Bv; }

    int wm = (wave & 1) * 64, wn = (wave >> 1) * 64;
    int r0 = tid >> 2, c0 = (tid & 3) * 8;

    f32x4 acc[4][4];
#pragma unroll
    for (int i = 0; i < 4; i++)
#pragma unroll
        for (int j = 0; j < 4; j++) acc[i][j] = (f32x4){0.f, 0.f, 0.f, 0.f};

    for (int k0 = 0; k0 < K; k0 += 32) {
        __syncthreads();
        lds16(A + (size_t)(m0 + r0) * K + k0 + c0, As + wave * 512);
        lds16(A + (size_t)(m0 + 64 + r0) * K + k0 + c0, As + 2048 + wave * 512);
        lds16(Bt + (size_t)(n0 + r0) * K + k0 + c0, Bs + wave * 512);
        lds16(Bt + (size_t)(n0 + 64 + r0) * K + k0 + c0, Bs + 2048 + wave * 512);
        __syncthreads();
        bf16x8 af[4], bfr[4];
#pragma unroll
        for (int t = 0; t < 4; t++) {
            af[t] = *(const bf16x8*)(As + (wm + t * 16 + l16) * 32 + quad * 8);
            bfr[t] = *(const bf16x8*)(Bs + (wn + t * 16 + l16) * 32 + quad * 8);
        }
#pragma unroll
        for (int mt = 0; mt < 4; mt++)
#pragma unroll
            for (int nt = 0; nt < 4; nt++)
                acc[mt][nt] = mfma16(af[mt], bfr[nt], acc[mt][nt]);
    }

#pragma unroll
    for (int mt = 0; mt < 4; mt++) {
#pragma unroll
        for (int nt = 0; nt < 4; nt++) {
#pragma unroll
            for (int r = 0; r < 4; r++) {
                int gm = m0 + wm + mt * 16 + quad * 4 + r;
                int gn = n0 + wn + nt * 16 + l16;
                float v = acc[mt][nt][r];
                if (EPI == 1) {
                    Cout[(size_t)gm * N + gn] = v;
                } else {
                    int b = gm >> 11, s = gm & 2047;
                    int h = gn >> 6, dk = gn & 63;
                    short bv = bf16b(v);
                    if (blockIdx.z == 0)
                        Cq[(((size_t)(b * HH + h)) * SS + s) * DKK + dk] = bv;
                    else if (blockIdx.z == 1)
                        Ck[(((size_t)(b * HH + h)) * SS + s) * DKK + dk] = bv;
                    else
                        Cvt[(((size_t)(b * HH + h)) * DKK + dk) * SS + s] = bv;
                }
            }
        }
    }
}

// ---------------- attention: software-pipelined, XCD-local ----------------
// grid (bh=32, qblk=32): blockIdx.x = bh, so all 32 q-blocks of one bh land on
// XCD bh%8 (linear ids differ by 32, 32%8==0) -> K/V (512KB/bh, 4 bh = 2MB)
// stays resident in that XCD's 4MB L2.
// Per iter: issue kf(kc+64) + vf(kc) + bias(kc) loads FIRST, then compute on
// kf(kc) prefetched one full iteration ago. unroll 2 renames cur/next copies.
__global__ __launch_bounds__(256) void attn(
    const short* __restrict__ Q, const short* __restrict__ Kmat,
    const short* __restrict__ Vt, const float* __restrict__ btab,
    short* __restrict__ O) {
    __shared__ float bias_s[4096];
    __shared__ short P_s[4][16 * 64];
    int tid = threadIdx.x;
    int wave = tid >> 6, lane = tid & 63;
    int quad = lane >> 4, l16 = lane & 15;
    int bh = blockIdx.x;
    int h = bh & 15, b = bh >> 4;
    int q0 = blockIdx.y * 64 + wave * 16;

    const float* bt = btab + h * 4095;
    for (int i = tid; i < 4095; i += 256) bias_s[i] = bt[i];
    __syncthreads();

    const short* Qb = Q + (size_t)bh * SS * DKK;
    const short* Kb = Kmat + (size_t)bh * SS * DKK;
    const short* Vb = Vt + (size_t)bh * DKK * SS;

    bf16x8 qf0 = *(const bf16x8*)(Qb + (q0 + l16) * DKK + quad * 8);
    bf16x8 qf1 = *(const bf16x8*)(Qb + (q0 + l16) * DKK + 32 + quad * 8);

    f32x4 o[4];
#pragma unroll
    for (int i = 0; i < 4; i++) o[i] = (f32x4){0.f, 0.f, 0.f, 0.f};
    f32x4 lacc = (f32x4){0.f, 0.f, 0.f, 0.f};

    bf16x8 onesf;
    short onev = (l16 == 0) ? (short)0x3F80 : (short)0;
#pragma unroll
    for (int i = 0; i < 8; i++) onesf[i] = onev;

    short* Pw = &P_s[wave][0];
    int gxor = l16 & 7;
    int ghalf = quad >> 1;
    int wbase = l16 * 64 + (quad & 1) * 4;              // + g*8 (shorts)
    int ra0 = l16 * 64 + ((quad ^ gxor) * 8);           // pf0 read (shorts)
    int ra1 = l16 * 64 + (((4 + quad) ^ gxor) * 8);     // pf1 read
    int dconst = 2047 + quad * 4 - q0 - l16;            // + kc + kt*16 + r

    // ---- prologue: prefetch kf for kc=0 ----
    bf16x8 kcur[4][2];
#pragma unroll
    for (int kt = 0; kt < 4; kt++) {
        kcur[kt][0] = *(const bf16x8*)(Kb + (kt * 16 + l16) * DKK + quad * 8);
        kcur[kt][1] = *(const bf16x8*)(Kb + (kt * 16 + l16) * DKK + 32 + quad * 8);
    }

#pragma unroll 2
    for (int kc = 0; kc < SS; kc += 64) {
        int kn = (kc + 64) & (SS - 1); // wraps to 0 on last iter (discarded)
        // ---- prefetch next K chunk (consumed next iteration) ----
        bf16x8 knext[4][2];
#pragma unroll
        for (int kt = 0; kt < 4; kt++) {
            knext[kt][0] = *(const bf16x8*)(Kb + (kn + kt * 16 + l16) * DKK + quad * 8);
            knext[kt][1] = *(const bf16x8*)(Kb + (kn + kt * 16 + l16) * DKK + 32 + quad * 8);
        }
        // ---- V frags for this chunk (consumed at end of this iteration) ----
        bf16x8 vf[4][2];
#pragma unroll
        for (int nt = 0; nt < 4; nt++) {
            vf[nt][0] = *(const bf16x8*)(Vb + (size_t)(nt * 16 + l16) * SS + kc + quad * 8);
            vf[nt][1] = *(const bf16x8*)(Vb + (size_t)(nt * 16 + l16) * SS + kc + 32 + quad * 8);
        }
        // ---- bias for this chunk (LDS, ~120cyc, covered by QK below) ----
        float bcur[4][4];
#pragma unroll
        for (int kt = 0; kt < 4; kt++)
#pragma unroll
            for (int r = 0; r < 4; r++)
                bcur[kt][r] = bias_s[dconst + kc + kt * 16 + r];
        // ---- QK^T on current (prefetched) K: S^T[key][q] ----
        f32x4 s[4];
#pragma unroll
        for (int kt = 0; kt < 4; kt++) {
            s[kt] = mfma16(kcur[kt][0], qf0, (f32x4){0.f, 0.f, 0.f, 0.f});
            s[kt] = mfma16(kcur[kt][1], qf1, s[kt]);
        }
        // ---- p = 2^(s*log2e + b*log2e); pack to bf16 pairs; swizzled LDS write ----
#pragma unroll
        for (int kt = 0; kt < 4; kt++) {
            unsigned u[4];
#pragma unroll
            for (int r = 0; r < 4; r++) {
                float p = __builtin_amdgcn_exp2f(fmaf(s[kt][r], 1.44269504f, bcur[kt][r]));
                u[r] = f2u(p) + 0x8000u; // round-half-up bf16 in high 16
            }
            unsigned d0 = __builtin_amdgcn_perm(u[1], u[0], 0x07060302u);
            unsigned d1 = __builtin_amdgcn_perm(u[3], u[2], 0x07060302u);
            int g = (kt * 2 + ghalf) ^ gxor;
            *(i32x2*)(Pw + wbase + g * 8) = (i32x2){(int)d0, (int)d1};
        }
        // wave-local LDS exchange; DS pipe in-order per wave (verified r2).
        __asm__ __volatile__("" ::: "memory");
        bf16x8 pf0 = *(const bf16x8*)(Pw + ra0);
        bf16x8 pf1 = *(const bf16x8*)(Pw + ra1);
        // ---- row-sum via ones-column MFMA ----
        lacc = mfma16(pf0, onesf, lacc);
        lacc = mfma16(pf1, onesf, lacc);
        // ---- PV ----
#pragma unroll
        for (int nt = 0; nt < 4; nt++) {
            o[nt] = mfma16(pf0, vf[nt][0], o[nt]);
            o[nt] = mfma16(pf1, vf[nt][1], o[nt]);
        }
        // ---- rotate pipeline (renamed away by unroll 2) ----
#pragma unroll
        for (int kt = 0; kt < 4; kt++) {
            kcur[kt][0] = knext[kt][0];
            kcur[kt][1] = knext[kt][1];
        }
    }

    float inv[4];
#pragma unroll
    for (int r = 0; r < 4; r++) {
        float l = __shfl(lacc[r], lane & 48); // broadcast from l16==0 of this quad
        inv[r] = 1.f / l;
    }
#pragma unroll
    for (int nt = 0; nt < 4; nt++)
#pragma unroll
        for (int r = 0; r < 4; r++) {
            int qrow = q0 + quad * 4 + r;
            int dk = nt * 16 + l16;
            O[((size_t)(b * SS + qrow)) * (HH * DKK) + h * DKK + dk] =
                bf16b(o[nt][r] * inv[r]);
        }
}

extern "C" void kernel_launch(void* const* d_in, const int* in_sizes, int n_in,
                              void* d_out, int out_size, void* d_ws, size_t ws_size,
                              hipStream_t stream) {
    const float* hs = (const float*)d_in[0];
    const float* Wq = (const float*)d_in[1];
    const float* Wk = (const float*)d_in[2];
    const float* Wv = (const float*)d_in[3];
    const float* Wo = (const float*)d_in[4];
    const float* rb = (const float*)d_in[5];
    float* out = (float*)d_out;

    char* ws = (char*)d_ws;
    size_t off = 0;
    auto alloc = [&](size_t bytes) -> void* {
        void* p = (void*)(ws + off);
        off += (bytes + 255) & ~(size_t)255;
        return p;
    };
    const size_t M = (size_t)BB * SS; // 4096
    short* hsb = (short*)alloc(M * DD * 2);
    short* WqT = (short*)alloc((size_t)DD * DD * 2);
    short* WkT = (short*)alloc((size_t)DD * DD * 2);
    short* WvT = (short*)alloc((size_t)DD * DD * 2);
    short* WoT = (short*)alloc((size_t)DD * DD * 2);
    short* Qb  = (short*)alloc(M * DD * 2);
    short* Kb  = (short*)alloc(M * DD * 2);
    short* VTb = (short*)alloc(M * DD * 2);
    short* Ab  = (short*)alloc(M * DD * 2);
    float* btab = (float*)alloc((size_t)HH * 4095 * 4);

    int nHS = (int)(M * DD);
    cvt_bf16<<<nHS / 1024, 256, 0, stream>>>(hs, hsb, nHS);
    transpose_w<<<dim3(32, 32, 4), 256, 0, stream>>>(Wq, Wk, Wv, Wo, WqT, WkT, WvT, WoT);
    build_bias<<<(HH * 4095 + 255) / 256, 256, 0, stream>>>(rb, btab);
    gemm_bt<0><<<dim3(8, 32, 3), 256, 0, stream>>>(hsb, WqT, WkT, WvT, Qb, Kb, VTb, nullptr);
    attn<<<dim3(32, 32), 256, 0, stream>>>(Qb, Kb, VTb, btab, Ab);
    gemm_bt<1><<<dim3(8, 32, 1), 256, 0, stream>>>(Ab, WoT, nullptr, nullptr,
                                                   nullptr, nullptr, nullptr, out);
}

// Round 4
// 222.515 us; speedup vs baseline: 1.9569x; 1.7296x over previous
//
#include <hip/hip_runtime.h>

#define HH 16
#define DKK 64
#define SS 2048
#define BB 2
#define DD 1024

typedef __attribute__((ext_vector_type(4))) float f32x4;
typedef __attribute__((ext_vector_type(8))) short bf16x8;
typedef __attribute__((ext_vector_type(4))) short s16x4;
typedef __attribute__((ext_vector_type(2))) int i32x2;

__device__ __forceinline__ short bf16b(float f) {
    union { float f; unsigned u; } x; x.f = f;
    unsigned r = (x.u + 0x7fffu + ((x.u >> 16) & 1u)) >> 16;
    return (short)r;
}

__device__ __forceinline__ unsigned f2u(float f) {
    union { float f; unsigned u; } x; x.f = f;
    return x.u;
}

__device__ __forceinline__ f32x4 mfma16(bf16x8 a, bf16x8 b, f32x4 c) {
    return __builtin_amdgcn_mfma_f32_16x16x32_bf16(a, b, c, 0, 0, 0);
}

__device__ __forceinline__ void lds16(const short* g, short* l) {
    __builtin_amdgcn_global_load_lds(
        (const __attribute__((address_space(1))) void*)g,
        (__attribute__((address_space(3))) void*)l, 16, 0, 0);
}

// ---------------- fp32 -> bf16 cast (contiguous) ----------------
__global__ __launch_bounds__(256) void cvt_bf16(const float* __restrict__ x,
                                                short* __restrict__ y, int n) {
    int i = (blockIdx.x * 256 + threadIdx.x) * 4;
    if (i >= n) return;
    f32x4 v = *(const f32x4*)(x + i);
    s16x4 o;
    o.x = bf16b(v.x); o.y = bf16b(v.y); o.z = bf16b(v.z); o.w = bf16b(v.w);
    *(s16x4*)(y + i) = o;
}

// ---------------- weight transpose+cast: W[K][N] fp32 -> Wt[N][K] bf16 ----------------
__global__ __launch_bounds__(256) void transpose_w(
    const float* __restrict__ W0, const float* __restrict__ W1,
    const float* __restrict__ W2, const float* __restrict__ W3,
    short* __restrict__ T0, short* __restrict__ T1,
    short* __restrict__ T2, short* __restrict__ T3) {
    const float* W; short* T;
    switch (blockIdx.z) {
        case 0: W = W0; T = T0; break;
        case 1: W = W1; T = T1; break;
        case 2: W = W2; T = T2; break;
        default: W = W3; T = T3; break;
    }
    __shared__ short tile[32][33];
    int n0 = blockIdx.x * 32, k0 = blockIdx.y * 32;
    int tx = threadIdx.x & 31;
    int ty = (threadIdx.x >> 5) * 4;
#pragma unroll
    for (int i = 0; i < 4; i++)
        tile[ty + i][tx] = bf16b(W[(k0 + ty + i) * DD + n0 + tx]);
    __syncthreads();
#pragma unroll
    for (int i = 0; i < 4; i++)
        T[(n0 + ty + i) * DD + k0 + tx] = tile[tx][ty + i];
}

// ---------------- bias table: tab[h][delta+2047] = bias * log2(e) ----------------
__global__ __launch_bounds__(256) void build_bias(const float* __restrict__ rb,
                                                  float* __restrict__ tab) {
    int idx = blockIdx.x * 256 + threadIdx.x;
    if (idx >= HH * 4095) return;
    int h = idx / 4095, d = idx % 4095;
    int rel = d - 2047; // k - q
    int bucket = (rel > 0) ? 16 : 0;
    unsigned r = (rel < 0) ? (unsigned)(-rel) : (unsigned)rel;
    int add;
    if (r < 8) add = (int)r;
    else {
        int e = 31 - __clz(r);
        unsigned long long r2 = (unsigned long long)r * (unsigned long long)r;
        int f = 2 * e + ((r2 >= (2ull << (2 * e))) ? 1 : 0); // floor(2*log2 r)
        add = 8 + (f - 6);
        if (add > 15) add = 15;
    }
    bucket += add;
    tab[h * 4095 + d] = rb[bucket * HH + h] * 1.44269504f;
}

// ---------------- 128x128 tile bf16 GEMM: C = A[M][K] * Bt[N][K]^T ----------------
template <int EPI>
__global__ __launch_bounds__(256) void gemm_bt(
    const short* __restrict__ A,
    const short* __restrict__ Bq, const short* __restrict__ Bk, const short* __restrict__ Bv,
    short* __restrict__ Cq, short* __restrict__ Ck, short* __restrict__ Cvt,
    float* __restrict__ Cout) {
    const int K = 1024, N = 1024;
    __shared__ short As[128 * 32];
    __shared__ short Bs[128 * 32];
    int tid = threadIdx.x;
    int wave = tid >> 6, lane = tid & 63;
    int quad = lane >> 4, l16 = lane & 15;
    int m0 = blockIdx.y * 128, n0 = blockIdx.x * 128;
    const short* Bt = Bq;
    if (EPI == 0) { if (blockIdx.z == 1) Bt = Bk; else if (blockIdx.z == 2) Bt = Bv; }

    int wm = (wave & 1) * 64, wn = (wave >> 1) * 64;
    int r0 = tid >> 2, c0 = (tid & 3) * 8;

    f32x4 acc[4][4];
#pragma unroll
    for (int i = 0; i < 4; i++)
#pragma unroll
        for (int j = 0; j < 4; j++) acc[i][j] = (f32x4){0.f, 0.f, 0.f, 0.f};

    for (int k0 = 0; k0 < K; k0 += 32) {
        __syncthreads();
        lds16(A + (size_t)(m0 + r0) * K + k0 + c0, As + wave * 512);
        lds16(A + (size_t)(m0 + 64 + r0) * K + k0 + c0, As + 2048 + wave * 512);
        lds16(Bt + (size_t)(n0 + r0) * K + k0 + c0, Bs + wave * 512);
        lds16(Bt + (size_t)(n0 + 64 + r0) * K + k0 + c0, Bs + 2048 + wave * 512);
        __syncthreads();
        bf16x8 af[4], bfr[4];
#pragma unroll
        for (int t = 0; t < 4; t++) {
            af[t] = *(const bf16x8*)(As + (wm + t * 16 + l16) * 32 + quad * 8);
            bfr[t] = *(const bf16x8*)(Bs + (wn + t * 16 + l16) * 32 + quad * 8);
        }
#pragma unroll
        for (int mt = 0; mt < 4; mt++)
#pragma unroll
            for (int nt = 0; nt < 4; nt++)
                acc[mt][nt] = mfma16(af[mt], bfr[nt], acc[mt][nt]);
    }

#pragma unroll
    for (int mt = 0; mt < 4; mt++) {
#pragma unroll
        for (int nt = 0; nt < 4; nt++) {
#pragma unroll
            for (int r = 0; r < 4; r++) {
                int gm = m0 + wm + mt * 16 + quad * 4 + r;
                int gn = n0 + wn + nt * 16 + l16;
                float v = acc[mt][nt][r];
                if (EPI == 1) {
                    Cout[(size_t)gm * N + gn] = v;
                } else {
                    int b = gm >> 11, s = gm & 2047;
                    int h = gn >> 6, dk = gn & 63;
                    short bv = bf16b(v);
                    if (blockIdx.z == 0)
                        Cq[(((size_t)(b * HH + h)) * SS + s) * DKK + dk] = bv;
                    else if (blockIdx.z == 1)
                        Ck[(((size_t)(b * HH + h)) * SS + s) * DKK + dk] = bv;
                    else
                        Cvt[(((size_t)(b * HH + h)) * DKK + dk) * SS + s] = bv;
                }
            }
        }
    }
}

// ---------------- attention: m97-style DMA double-buffered LDS staging ----------------
// grid (bh=32, qblk=16), block 256 = 4 waves; wave owns 32 q-rows (2 strips of 16),
// 64 keys/iter. K-tile [key][dk] and V^T-tile [dk][key] staged via global_load_lds
// (zero VGPR cost) with 16B-granule XOR swizzle (slot = granule ^ (row&7)) applied
// on the GLOBAL address so fragment ds_read_b128 is bank-conflict-free.
// kf/vf are q-independent: read once, used by both strips (halves LDS BW/work).
// Bias: |delta|>=128 clamps to bucket 15/31 -> outside the diagonal band the whole
// chunk uses a scalar constant (no LDS reads). blockIdx.x=bh keeps K/V XCD-L2-local.
__global__ __launch_bounds__(256, 2) void attn(
    const short* __restrict__ Q, const short* __restrict__ Kmat,
    const short* __restrict__ Vt, const float* __restrict__ btab,
    short* __restrict__ O) {
    __shared__ short Ks[2][64 * 64];
    __shared__ short Vs[2][64 * 64];
    __shared__ float bias_s[2176];
    __shared__ short P_s[4][16 * 64];

    int tid = threadIdx.x;
    int wave = tid >> 6, lane = tid & 63;
    int quad = lane >> 4, l16 = lane & 15;
    int bh = blockIdx.x;
    int h = bh & 15, b = bh >> 4;
    int q0b = blockIdx.y * 128;
    int q0w = q0b + wave * 32;

    const short* Qb = Q + (size_t)bh * SS * DKK;
    const short* Kb = Kmat + (size_t)bh * SS * DKK;
    const short* Vb = Vt + (size_t)bh * DKK * SS;
    const float* bt = btab + h * 4095;

    // bias window: global idx = 2047 + (k-q); window [woff, woff+2175]
    int woff = 1920 - q0b;
    for (int i = tid; i < 2176; i += 256) {
        int gi = woff + i;
        bias_s[i] = bt[gi > 4094 ? 4094 : gi];
    }
    float blo = bt[2047 - 128]; // delta <= -128 -> bucket 15
    float bhi = bt[2047 + 128]; // delta >= +128 -> bucket 31

    // staging addresses (16B granules, XOR swizzle on global side)
    int kro = tid >> 3;                 // 0..31
    int gk = (tid & 7) ^ (kro & 7);     // granule to fetch
    const short* Kg0 = Kb + (size_t)kro * DKK + gk * 8;
    const short* Kg1 = Kb + (size_t)(kro + 32) * DKK + gk * 8;
    const short* Vg0 = Vb + (size_t)kro * SS + gk * 8;
    const short* Vg1 = Vb + (size_t)(kro + 32) * SS + gk * 8;

    // Q fragments: 2 strips x 2 halves
    bf16x8 qf[2][2];
#pragma unroll
    for (int qs = 0; qs < 2; qs++) {
        qf[qs][0] = *(const bf16x8*)(Qb + (q0w + qs * 16 + l16) * DKK + quad * 8);
        qf[qs][1] = *(const bf16x8*)(Qb + (q0w + qs * 16 + l16) * DKK + 32 + quad * 8);
    }

    f32x4 o[2][4];
#pragma unroll
    for (int qs = 0; qs < 2; qs++)
#pragma unroll
        for (int i = 0; i < 4; i++) o[qs][i] = (f32x4){0.f, 0.f, 0.f, 0.f};
    f32x4 lacc[2];
    lacc[0] = (f32x4){0.f, 0.f, 0.f, 0.f};
    lacc[1] = (f32x4){0.f, 0.f, 0.f, 0.f};

    bf16x8 onesf;
    short onev = (l16 == 0) ? (short)0x3F80 : (short)0;
#pragma unroll
    for (int i = 0; i < 8; i++) onesf[i] = onev;

    short* Pw = &P_s[wave][0];
    int gxor = l16 & 7;
    int ghalf = quad >> 1;
    int wbase = l16 * 64 + (quad & 1) * 4;           // + g*8 (shorts)
    int ra0 = l16 * 64 + ((quad ^ gxor) * 8);        // pf0 read
    int ra1 = l16 * 64 + (((4 + quad) ^ gxor) * 8);  // pf1 read
    // window bias idx = bidx + kc + kt*16 + r - qs*16
    int bidx = 127 + quad * 4 - wave * 32 - l16;
    // fragment LDS slot swizzle
    int sl0 = (quad ^ gxor) * 8;        // half 0 granule slot (shorts)
    int sl1 = ((4 + quad) ^ gxor) * 8;  // half 1

    // prologue: stage chunk 0 into buf 0
    lds16(Kg0, &Ks[0][wave * 512]);
    lds16(Kg1, &Ks[0][2048 + wave * 512]);
    lds16(Vg0, &Vs[0][wave * 512]);
    lds16(Vg1, &Vs[0][2048 + wave * 512]);

    int cur = 0;
    for (int kc = 0; kc < SS; kc += 64) {
        __syncthreads(); // drains prev-iter DMA (vmcnt 0) + all waves' frag reads
        int kn = (kc + 64) & (SS - 1); // last iter wraps to 0 (discarded)
        int nxt = cur ^ 1;
        lds16(Kg0 + (size_t)kn * DKK, &Ks[nxt][wave * 512]);
        lds16(Kg1 + (size_t)kn * DKK, &Ks[nxt][2048 + wave * 512]);
        lds16(Vg0 + kn, &Vs[nxt][wave * 512]);
        lds16(Vg1 + kn, &Vs[nxt][2048 + wave * 512]);

        const short* Ksc = &Ks[cur][0];
        const short* Vsc = &Vs[cur][0];

        // ---- QK^T for both strips (kf shared): S^T[key][q] ----
        f32x4 s[2][4];
#pragma unroll
        for (int kt = 0; kt < 4; kt++) {
            int row = (kt * 16 + l16) * 64;
            bf16x8 kf0 = *(const bf16x8*)(Ksc + row + sl0);
            bf16x8 kf1 = *(const bf16x8*)(Ksc + row + sl1);
            s[0][kt] = mfma16(kf0, qf[0][0], (f32x4){0.f, 0.f, 0.f, 0.f});
            s[0][kt] = mfma16(kf1, qf[0][1], s[0][kt]);
            s[1][kt] = mfma16(kf0, qf[1][0], (f32x4){0.f, 0.f, 0.f, 0.f});
            s[1][kt] = mfma16(kf1, qf[1][1], s[1][kt]);
        }
        // ---- V fragments (shared by both strips) ----
        bf16x8 vf[4][2];
#pragma unroll
        for (int nt = 0; nt < 4; nt++) {
            int row = (nt * 16 + l16) * 64;
            vf[nt][0] = *(const bf16x8*)(Vsc + row + sl0);
            vf[nt][1] = *(const bf16x8*)(Vsc + row + sl1);
        }

        // ---- per strip: exp -> P(LDS) -> rowsum + PV ----
#pragma unroll
        for (int qs = 0; qs < 2; qs++) {
            int q0s = q0w + qs * 16;
            bool nearb = (kc > q0s - 191) && (kc < q0s + 143);
            float bconst = (kc <= q0s - 191) ? blo : bhi;
#pragma unroll
            for (int kt = 0; kt < 4; kt++) {
                unsigned u[4];
#pragma unroll
                for (int r = 0; r < 4; r++) {
                    float bv = nearb ? bias_s[bidx + kc + kt * 16 + r - qs * 16]
                                     : bconst;
                    float p = __builtin_amdgcn_exp2f(
                        fmaf(s[qs][kt][r], 1.44269504f, bv));
                    u[r] = f2u(p) + 0x8000u; // round-half-up bf16 in hi16
                }
                unsigned d0 = __builtin_amdgcn_perm(u[1], u[0], 0x07060302u);
                unsigned d1 = __builtin_amdgcn_perm(u[3], u[2], 0x07060302u);
                int g = (kt * 2 + ghalf) ^ gxor;
                *(i32x2*)(Pw + wbase + g * 8) = (i32x2){(int)d0, (int)d1};
            }
            // wave-local exchange; DS pipe is in-order per wave
            __asm__ __volatile__("" ::: "memory");
            bf16x8 pf0 = *(const bf16x8*)(Pw + ra0);
            bf16x8 pf1 = *(const bf16x8*)(Pw + ra1);
            lacc[qs] = mfma16(pf0, onesf, lacc[qs]);
            lacc[qs] = mfma16(pf1, onesf, lacc[qs]);
#pragma unroll
            for (int nt = 0; nt < 4; nt++) {
                o[qs][nt] = mfma16(pf0, vf[nt][0], o[qs][nt]);
                o[qs][nt] = mfma16(pf1, vf[nt][1], o[qs][nt]);
            }
            __asm__ __volatile__("" ::: "memory"); // reads before next strip's writes
        }
        cur ^= 1;
    }

#pragma unroll
    for (int qs = 0; qs < 2; qs++) {
        float inv[4];
#pragma unroll
        for (int r = 0; r < 4; r++) {
            float l = __shfl(lacc[qs][r], lane & 48);
            inv[r] = 1.f / l;
        }
#pragma unroll
        for (int nt = 0; nt < 4; nt++)
#pragma unroll
            for (int r = 0; r < 4; r++) {
                int qrow = q0w + qs * 16 + quad * 4 + r;
                int dk = nt * 16 + l16;
                O[((size_t)(b * SS + qrow)) * (HH * DKK) + h * DKK + dk] =
                    bf16b(o[qs][nt][r] * inv[r]);
            }
    }
}

extern "C" void kernel_launch(void* const* d_in, const int* in_sizes, int n_in,
                              void* d_out, int out_size, void* d_ws, size_t ws_size,
                              hipStream_t stream) {
    const float* hs = (const float*)d_in[0];
    const float* Wq = (const float*)d_in[1];
    const float* Wk = (const float*)d_in[2];
    const float* Wv = (const float*)d_in[3];
    const float* Wo = (const float*)d_in[4];
    const float* rb = (const float*)d_in[5];
    float* out = (float*)d_out;

    char* ws = (char*)d_ws;
    size_t off = 0;
    auto alloc = [&](size_t bytes) -> void* {
        void* p = (void*)(ws + off);
        off += (bytes + 255) & ~(size_t)255;
        return p;
    };
    const size_t M = (size_t)BB * SS; // 4096
    short* hsb = (short*)alloc(M * DD * 2);
    short* WqT = (short*)alloc((size_t)DD * DD * 2);
    short* WkT = (short*)alloc((size_t)DD * DD * 2);
    short* WvT = (short*)alloc((size_t)DD * DD * 2);
    short* WoT = (short*)alloc((size_t)DD * DD * 2);
    short* Qb  = (short*)alloc(M * DD * 2);
    short* Kb  = (short*)alloc(M * DD * 2);
    short* VTb = (short*)alloc(M * DD * 2);
    short* Ab  = (short*)alloc(M * DD * 2);
    float* btab = (float*)alloc((size_t)HH * 4095 * 4);

    int nHS = (int)(M * DD);
    cvt_bf16<<<nHS / 1024, 256, 0, stream>>>(hs, hsb, nHS);
    transpose_w<<<dim3(32, 32, 4), 256, 0, stream>>>(Wq, Wk, Wv, Wo, WqT, WkT, WvT, WoT);
    build_bias<<<(HH * 4095 + 255) / 256, 256, 0, stream>>>(rb, btab);
    gemm_bt<0><<<dim3(8, 32, 3), 256, 0, stream>>>(hsb, WqT, WkT, WvT, Qb, Kb, VTb, nullptr);
    attn<<<dim3(32, 16), 256, 0, stream>>>(Qb, Kb, VTb, btab, Ab);
    gemm_bt<1><<<dim3(8, 32, 1), 256, 0, stream>>>(Ab, WoT, nullptr, nullptr,
                                                   nullptr, nullptr, nullptr, out);
}

// Round 5
// 196.263 us; speedup vs baseline: 2.2186x; 1.1338x over previous
//
#include <hip/hip_runtime.h>

#define HH 16
#define DKK 64
#define SS 2048
#define BB 2
#define DD 1024

typedef __attribute__((ext_vector_type(4))) float f32x4;
typedef __attribute__((ext_vector_type(8))) short bf16x8;
typedef __attribute__((ext_vector_type(4))) short s16x4;
typedef __attribute__((ext_vector_type(2))) int i32x2;

__device__ __forceinline__ short bf16b(float f) {
    union { float f; unsigned u; } x; x.f = f;
    unsigned r = (x.u + 0x7fffu + ((x.u >> 16) & 1u)) >> 16;
    return (short)r;
}

__device__ __forceinline__ unsigned f2u(float f) {
    union { float f; unsigned u; } x; x.f = f;
    return x.u;
}

__device__ __forceinline__ f32x4 mfma16(bf16x8 a, bf16x8 b, f32x4 c) {
    return __builtin_amdgcn_mfma_f32_16x16x32_bf16(a, b, c, 0, 0, 0);
}

__device__ __forceinline__ void lds16(const short* g, short* l) {
    __builtin_amdgcn_global_load_lds(
        (const __attribute__((address_space(1))) void*)g,
        (__attribute__((address_space(3))) void*)l, 16, 0, 0);
}

// ---------------- fp32 -> bf16 cast (contiguous) ----------------
__global__ __launch_bounds__(256) void cvt_bf16(const float* __restrict__ x,
                                                short* __restrict__ y, int n) {
    int i = (blockIdx.x * 256 + threadIdx.x) * 4;
    if (i >= n) return;
    f32x4 v = *(const f32x4*)(x + i);
    s16x4 o;
    o.x = bf16b(v.x); o.y = bf16b(v.y); o.z = bf16b(v.z); o.w = bf16b(v.w);
    *(s16x4*)(y + i) = o;
}

// ---------------- weight transpose+cast: W[K][N] fp32 -> Wt[N][K] bf16 ----------------
__global__ __launch_bounds__(256) void transpose_w(
    const float* __restrict__ W0, const float* __restrict__ W1,
    const float* __restrict__ W2, const float* __restrict__ W3,
    short* __restrict__ T0, short* __restrict__ T1,
    short* __restrict__ T2, short* __restrict__ T3) {
    const float* W; short* T;
    switch (blockIdx.z) {
        case 0: W = W0; T = T0; break;
        case 1: W = W1; T = T1; break;
        case 2: W = W2; T = T2; break;
        default: W = W3; T = T3; break;
    }
    __shared__ short tile[32][33];
    int n0 = blockIdx.x * 32, k0 = blockIdx.y * 32;
    int tx = threadIdx.x & 31;
    int ty = (threadIdx.x >> 5) * 4;
#pragma unroll
    for (int i = 0; i < 4; i++)
        tile[ty + i][tx] = bf16b(W[(k0 + ty + i) * DD + n0 + tx]);
    __syncthreads();
#pragma unroll
    for (int i = 0; i < 4; i++)
        T[(n0 + ty + i) * DD + k0 + tx] = tile[tx][ty + i];
}

// ---------------- bias table: tab[h][delta+2047] = bias * log2(e) ----------------
__global__ __launch_bounds__(256) void build_bias(const float* __restrict__ rb,
                                                  float* __restrict__ tab) {
    int idx = blockIdx.x * 256 + threadIdx.x;
    if (idx >= HH * 4095) return;
    int h = idx / 4095, d = idx % 4095;
    int rel = d - 2047; // k - q
    int bucket = (rel > 0) ? 16 : 0;
    unsigned r = (rel < 0) ? (unsigned)(-rel) : (unsigned)rel;
    int add;
    if (r < 8) add = (int)r;
    else {
        int e = 31 - __clz(r);
        unsigned long long r2 = (unsigned long long)r * (unsigned long long)r;
        int f = 2 * e + ((r2 >= (2ull << (2 * e))) ? 1 : 0); // floor(2*log2 r)
        add = 8 + (f - 6);
        if (add > 15) add = 15;
    }
    bucket += add;
    tab[h * 4095 + d] = rb[bucket * HH + h] * 1.44269504f;
}

// ---------------- fused QKV GEMM: C = A[4096][1024] * Wt[3072][1024]^T ----------------
// Wt = WqT|WkT|WvT contiguous. 128x128 tile; grid (24 n-tiles, 32 m-tiles):
// XCD = linear%8 = x%8 -> each XCD holds 3 n-bands (768 KB weights) in L2, A streams.
// Epilogue scatters: Q/K -> [B][H][S][DK] bf16, V -> [B][H][DK][S] bf16 (transposed).
__global__ __launch_bounds__(256) void gemm_qkv(
    const short* __restrict__ A, const short* __restrict__ Wt,
    short* __restrict__ Cq, short* __restrict__ Ck, short* __restrict__ Cvt) {
    const int K = 1024;
    __shared__ short As[128 * 32];
    __shared__ short Bs[128 * 32];
    int tid = threadIdx.x;
    int wave = tid >> 6, lane = tid & 63;
    int quad = lane >> 4, l16 = lane & 15;
    int m0 = blockIdx.y * 128, n0 = blockIdx.x * 128;

    int wm = (wave & 1) * 64, wn = (wave >> 1) * 64;
    int r0 = tid >> 2, c0 = (tid & 3) * 8;

    f32x4 acc[4][4];
#pragma unroll
    for (int i = 0; i < 4; i++)
#pragma unroll
        for (int j = 0; j < 4; j++) acc[i][j] = (f32x4){0.f, 0.f, 0.f, 0.f};

    for (int k0 = 0; k0 < K; k0 += 32) {
        __syncthreads();
        lds16(A + (size_t)(m0 + r0) * K + k0 + c0, As + wave * 512);
        lds16(A + (size_t)(m0 + 64 + r0) * K + k0 + c0, As + 2048 + wave * 512);
        lds16(Wt + (size_t)(n0 + r0) * K + k0 + c0, Bs + wave * 512);
        lds16(Wt + (size_t)(n0 + 64 + r0) * K + k0 + c0, Bs + 2048 + wave * 512);
        __syncthreads();
        bf16x8 af[4], bfr[4];
#pragma unroll
        for (int t = 0; t < 4; t++) {
            af[t] = *(const bf16x8*)(As + (wm + t * 16 + l16) * 32 + quad * 8);
            bfr[t] = *(const bf16x8*)(Bs + (wn + t * 16 + l16) * 32 + quad * 8);
        }
#pragma unroll
        for (int mt = 0; mt < 4; mt++)
#pragma unroll
            for (int nt = 0; nt < 4; nt++)
                acc[mt][nt] = mfma16(af[mt], bfr[nt], acc[mt][nt]);
    }

#pragma unroll
    for (int mt = 0; mt < 4; mt++) {
#pragma unroll
        for (int nt = 0; nt < 4; nt++) {
#pragma unroll
            for (int r = 0; r < 4; r++) {
                int gm = m0 + wm + mt * 16 + quad * 4 + r;
                int gn = n0 + wn + nt * 16 + l16;
                int b = gm >> 11, s = gm & 2047;
                int which = gn >> 10;       // wave-uniform per nt
                int h = (gn >> 6) & 15, dk = gn & 63;
                short bv = bf16b(acc[mt][nt][r]);
                if (which == 0)
                    Cq[(((size_t)(b * HH + h)) * SS + s) * DKK + dk] = bv;
                else if (which == 1)
                    Ck[(((size_t)(b * HH + h)) * SS + s) * DKK + dk] = bv;
                else
                    Cvt[(((size_t)(b * HH + h)) * DKK + dk) * SS + s] = bv;
            }
        }
    }
}

// ---------------- output projection: C[4096][1024] fp32 = A * WoT^T ----------------
// 64x128 tile -> grid (8 n, 64 m) = 512 blocks = 2/CU (vs 1/CU at 128x128).
// XCD = x%8 -> WoT n-band L2-resident per XCD.
__global__ __launch_bounds__(256) void gemm_out(
    const short* __restrict__ A, const short* __restrict__ Wt,
    float* __restrict__ Cout) {
    const int K = 1024, N = 1024;
    __shared__ short As[64 * 32];
    __shared__ short Bs[128 * 32];
    int tid = threadIdx.x;
    int wave = tid >> 6, lane = tid & 63;
    int quad = lane >> 4, l16 = lane & 15;
    int m0 = blockIdx.y * 64, n0 = blockIdx.x * 128;

    int wm = (wave & 1) * 32, wn = (wave >> 1) * 64;
    int r0 = tid >> 2, c0 = (tid & 3) * 8;

    f32x4 acc[2][4];
#pragma unroll
    for (int i = 0; i < 2; i++)
#pragma unroll
        for (int j = 0; j < 4; j++) acc[i][j] = (f32x4){0.f, 0.f, 0.f, 0.f};

    for (int k0 = 0; k0 < K; k0 += 32) {
        __syncthreads();
        lds16(A + (size_t)(m0 + r0) * K + k0 + c0, As + wave * 512);
        lds16(Wt + (size_t)(n0 + r0) * K + k0 + c0, Bs + wave * 512);
        lds16(Wt + (size_t)(n0 + 64 + r0) * K + k0 + c0, Bs + 2048 + wave * 512);
        __syncthreads();
        bf16x8 af[2], bfr[4];
#pragma unroll
        for (int t = 0; t < 2; t++)
            af[t] = *(const bf16x8*)(As + (wm + t * 16 + l16) * 32 + quad * 8);
#pragma unroll
        for (int t = 0; t < 4; t++)
            bfr[t] = *(const bf16x8*)(Bs + (wn + t * 16 + l16) * 32 + quad * 8);
#pragma unroll
        for (int mt = 0; mt < 2; mt++)
#pragma unroll
            for (int nt = 0; nt < 4; nt++)
                acc[mt][nt] = mfma16(af[mt], bfr[nt], acc[mt][nt]);
    }

#pragma unroll
    for (int mt = 0; mt < 2; mt++)
#pragma unroll
        for (int nt = 0; nt < 4; nt++)
#pragma unroll
            for (int r = 0; r < 4; r++) {
                int gm = m0 + wm + mt * 16 + quad * 4 + r;
                int gn = n0 + wn + nt * 16 + l16;
                Cout[(size_t)gm * N + gn] = acc[mt][nt][r];
            }
}

// ---------------- attention: DMA double-buffered, strip-interleaved ----------------
// grid (bh=32, qblk=16), block 256 = 4 waves; wave owns 32 q-rows (2 strips),
// 64 keys/iter. Round-5 changes vs r4: bias hoisted to registers at iter top
// (asm fences were pinning the LDS reads late), and both strips' exp/pack/P-writes
// complete before ONE fence, then both strips' P-reads + rowsum + PV (per-strip
// P regions) — removes one LDS write->read round-trip stall per iteration.
__global__ __launch_bounds__(256, 2) void attn(
    const short* __restrict__ Q, const short* __restrict__ Kmat,
    const short* __restrict__ Vt, const float* __restrict__ btab,
    short* __restrict__ O) {
    __shared__ short Ks[2][64 * 64];
    __shared__ short Vs[2][64 * 64];
    __shared__ float bias_s[2176];
    __shared__ short P_s[4][2][16 * 64];

    int tid = threadIdx.x;
    int wave = tid >> 6, lane = tid & 63;
    int quad = lane >> 4, l16 = lane & 15;
    int bh = blockIdx.x;
    int h = bh & 15, b = bh >> 4;
    int q0b = blockIdx.y * 128;
    int q0w = q0b + wave * 32;

    const short* Qb = Q + (size_t)bh * SS * DKK;
    const short* Kb = Kmat + (size_t)bh * SS * DKK;
    const short* Vb = Vt + (size_t)bh * DKK * SS;
    const float* bt = btab + h * 4095;

    int woff = 1920 - q0b;
    for (int i = tid; i < 2176; i += 256) {
        int gi = woff + i;
        bias_s[i] = bt[gi > 4094 ? 4094 : gi];
    }
    float blo = bt[2047 - 128]; // delta <= -128 -> clamped bucket
    float bhi = bt[2047 + 128]; // delta >= +128 -> clamped bucket

    int kro = tid >> 3;
    int gk = (tid & 7) ^ (kro & 7);
    const short* Kg0 = Kb + (size_t)kro * DKK + gk * 8;
    const short* Kg1 = Kb + (size_t)(kro + 32) * DKK + gk * 8;
    const short* Vg0 = Vb + (size_t)kro * SS + gk * 8;
    const short* Vg1 = Vb + (size_t)(kro + 32) * SS + gk * 8;

    bf16x8 qf[2][2];
#pragma unroll
    for (int qs = 0; qs < 2; qs++) {
        qf[qs][0] = *(const bf16x8*)(Qb + (q0w + qs * 16 + l16) * DKK + quad * 8);
        qf[qs][1] = *(const bf16x8*)(Qb + (q0w + qs * 16 + l16) * DKK + 32 + quad * 8);
    }

    f32x4 o[2][4];
#pragma unroll
    for (int qs = 0; qs < 2; qs++)
#pragma unroll
        for (int i = 0; i < 4; i++) o[qs][i] = (f32x4){0.f, 0.f, 0.f, 0.f};
    f32x4 lacc[2];
    lacc[0] = (f32x4){0.f, 0.f, 0.f, 0.f};
    lacc[1] = (f32x4){0.f, 0.f, 0.f, 0.f};

    bf16x8 onesf;
    short onev = (l16 == 0) ? (short)0x3F80 : (short)0;
#pragma unroll
    for (int i = 0; i < 8; i++) onesf[i] = onev;

    short* Pw = &P_s[wave][0][0];
    int gxor = l16 & 7;
    int ghalf = quad >> 1;
    int wbase = l16 * 64 + (quad & 1) * 4;
    int ra0 = l16 * 64 + ((quad ^ gxor) * 8);
    int ra1 = l16 * 64 + (((4 + quad) ^ gxor) * 8);
    int bidx = 127 + quad * 4 - wave * 32 - l16;
    int sl0 = (quad ^ gxor) * 8;
    int sl1 = ((4 + quad) ^ gxor) * 8;

    lds16(Kg0, &Ks[0][wave * 512]);
    lds16(Kg1, &Ks[0][2048 + wave * 512]);
    lds16(Vg0, &Vs[0][wave * 512]);
    lds16(Vg1, &Vs[0][2048 + wave * 512]);

    int cur = 0;
    for (int kc = 0; kc < SS; kc += 64) {
        __syncthreads(); // drains prev DMA (vmcnt 0) + all waves' frag reads
        int kn = (kc + 64) & (SS - 1);
        int nxt = cur ^ 1;
        lds16(Kg0 + (size_t)kn * DKK, &Ks[nxt][wave * 512]);
        lds16(Kg1 + (size_t)kn * DKK, &Ks[nxt][2048 + wave * 512]);
        lds16(Vg0 + kn, &Vs[nxt][wave * 512]);
        lds16(Vg1 + kn, &Vs[nxt][2048 + wave * 512]);

        // ---- bias into registers (wave-uniform branch per strip) ----
        float breg[2][16];
#pragma unroll
        for (int qs = 0; qs < 2; qs++) {
            int q0s = q0w + qs * 16;
            if (kc > q0s - 191 && kc < q0s + 143) {
#pragma unroll
                for (int kt = 0; kt < 4; kt++)
#pragma unroll
                    for (int r = 0; r < 4; r++)
                        breg[qs][kt * 4 + r] =
                            bias_s[bidx + kc + kt * 16 + r - qs * 16];
            } else {
                float bc = (kc <= q0s - 191) ? blo : bhi;
#pragma unroll
                for (int i = 0; i < 16; i++) breg[qs][i] = bc;
            }
        }

        const short* Ksc = &Ks[cur][0];
        const short* Vsc = &Vs[cur][0];

        // ---- QK^T both strips (kf shared): S^T[key][q] ----
        f32x4 s[2][4];
#pragma unroll
        for (int kt = 0; kt < 4; kt++) {
            int row = (kt * 16 + l16) * 64;
            bf16x8 kf0 = *(const bf16x8*)(Ksc + row + sl0);
            bf16x8 kf1 = *(const bf16x8*)(Ksc + row + sl1);
            s[0][kt] = mfma16(kf0, qf[0][0], (f32x4){0.f, 0.f, 0.f, 0.f});
            s[0][kt] = mfma16(kf1, qf[0][1], s[0][kt]);
            s[1][kt] = mfma16(kf0, qf[1][0], (f32x4){0.f, 0.f, 0.f, 0.f});
            s[1][kt] = mfma16(kf1, qf[1][1], s[1][kt]);
        }
        // ---- V fragments (shared by both strips) ----
        bf16x8 vf[4][2];
#pragma unroll
        for (int nt = 0; nt < 4; nt++) {
            int row = (nt * 16 + l16) * 64;
            vf[nt][0] = *(const bf16x8*)(Vsc + row + sl0);
            vf[nt][1] = *(const bf16x8*)(Vsc + row + sl1);
        }

        // ---- both strips: exp -> pack -> P write (separate regions) ----
#pragma unroll
        for (int qs = 0; qs < 2; qs++) {
#pragma unroll
            for (int kt = 0; kt < 4; kt++) {
                unsigned u[4];
#pragma unroll
                for (int r = 0; r < 4; r++) {
                    float p = __builtin_amdgcn_exp2f(
                        fmaf(s[qs][kt][r], 1.44269504f, breg[qs][kt * 4 + r]));
                    u[r] = f2u(p) + 0x8000u; // round-half-up bf16 in hi16
                }
                unsigned d0 = __builtin_amdgcn_perm(u[1], u[0], 0x07060302u);
                unsigned d1 = __builtin_amdgcn_perm(u[3], u[2], 0x07060302u);
                int g = (kt * 2 + ghalf) ^ gxor;
                *(i32x2*)(Pw + qs * 1024 + wbase + g * 8) = (i32x2){(int)d0, (int)d1};
            }
        }
        // single wave-local fence: DS pipe in-order per wave
        __asm__ __volatile__("" ::: "memory");
        // ---- both strips: P read -> rowsum + PV ----
#pragma unroll
        for (int qs = 0; qs < 2; qs++) {
            bf16x8 pf0 = *(const bf16x8*)(Pw + qs * 1024 + ra0);
            bf16x8 pf1 = *(const bf16x8*)(Pw + qs * 1024 + ra1);
            lacc[qs] = mfma16(pf0, onesf, lacc[qs]);
            lacc[qs] = mfma16(pf1, onesf, lacc[qs]);
#pragma unroll
            for (int nt = 0; nt < 4; nt++) {
                o[qs][nt] = mfma16(pf0, vf[nt][0], o[qs][nt]);
                o[qs][nt] = mfma16(pf1, vf[nt][1], o[qs][nt]);
            }
        }
        __asm__ __volatile__("" ::: "memory"); // reads before next iter's writes
        cur ^= 1;
    }

#pragma unroll
    for (int qs = 0; qs < 2; qs++) {
        float inv[4];
#pragma unroll
        for (int r = 0; r < 4; r++) {
            float l = __shfl(lacc[qs][r], lane & 48);
            inv[r] = 1.f / l;
        }
#pragma unroll
        for (int nt = 0; nt < 4; nt++)
#pragma unroll
            for (int r = 0; r < 4; r++) {
                int qrow = q0w + qs * 16 + quad * 4 + r;
                int dk = nt * 16 + l16;
                O[((size_t)(b * SS + qrow)) * (HH * DKK) + h * DKK + dk] =
                    bf16b(o[qs][nt][r] * inv[r]);
            }
    }
}

extern "C" void kernel_launch(void* const* d_in, const int* in_sizes, int n_in,
                              void* d_out, int out_size, void* d_ws, size_t ws_size,
                              hipStream_t stream) {
    const float* hs = (const float*)d_in[0];
    const float* Wq = (const float*)d_in[1];
    const float* Wk = (const float*)d_in[2];
    const float* Wv = (const float*)d_in[3];
    const float* Wo = (const float*)d_in[4];
    const float* rb = (const float*)d_in[5];
    float* out = (float*)d_out;

    char* ws = (char*)d_ws;
    size_t off = 0;
    auto alloc = [&](size_t bytes) -> void* {
        void* p = (void*)(ws + off);
        off += (bytes + 255) & ~(size_t)255;
        return p;
    };
    const size_t M = (size_t)BB * SS; // 4096
    short* hsb = (short*)alloc(M * DD * 2);
    // WqT/WkT/WvT MUST stay contiguous (2MB each, 256-aligned -> no padding):
    // gemm_qkv reads them as one [3072][1024] matrix.
    short* WqT = (short*)alloc((size_t)DD * DD * 2);
    short* WkT = (short*)alloc((size_t)DD * DD * 2);
    short* WvT = (short*)alloc((size_t)DD * DD * 2);
    short* WoT = (short*)alloc((size_t)DD * DD * 2);
    short* Qb  = (short*)alloc(M * DD * 2);
    short* Kb  = (short*)alloc(M * DD * 2);
    short* VTb = (short*)alloc(M * DD * 2);
    short* Ab  = (short*)alloc(M * DD * 2);
    float* btab = (float*)alloc((size_t)HH * 4095 * 4);

    int nHS = (int)(M * DD);
    cvt_bf16<<<nHS / 1024, 256, 0, stream>>>(hs, hsb, nHS);
    transpose_w<<<dim3(32, 32, 4), 256, 0, stream>>>(Wq, Wk, Wv, Wo, WqT, WkT, WvT, WoT);
    build_bias<<<(HH * 4095 + 255) / 256, 256, 0, stream>>>(rb, btab);
    gemm_qkv<<<dim3(24, 32), 256, 0, stream>>>(hsb, WqT, Qb, Kb, VTb);
    attn<<<dim3(32, 16), 256, 0, stream>>>(Qb, Kb, VTb, btab, Ab);
    gemm_out<<<dim3(8, 64), 256, 0, stream>>>(Ab, WoT, out);
}